// Round 2
// baseline (111.701 us; speedup 1.0000x reference)
//
#include <hip/hip_runtime.h>

// Problem constants (match reference)
#define BB 8192
#define SS 7
#define EE 2048
#define EV (EE / 4)   // float4 groups per row = 512
#define BPT 8         // batch rows per thread (weights amortized across these)

typedef float v4f __attribute__((ext_vector_type(4)));

// fast tanh: 1 - 2/(exp(2x)+1) via native exp2.
// Saturates correctly without a clamp: x>>0 -> exp2->inf -> rcp->0 -> +1;
// x<<0 -> exp2->0 -> rcp(1)=1 -> 1-2 = -1.  ~1e-6 abs err, threshold 2e-2.
__device__ __forceinline__ float fast_tanh(float x) {
    float e = exp2f(x * 2.885390081777927f);          // exp(2x), v_exp_f32
    return fmaf(-2.f, __builtin_amdgcn_rcpf(e + 1.f), 1.f);
}

__global__ __launch_bounds__(256, 4) void CSM_62216896250027_kernel(
    const v4f* __restrict__ Xv,
    const v4f* __restrict__ c1,   // (2, E)
    const v4f* __restrict__ c2,   // (2, E)
    const v4f* __restrict__ c3,   // (3, E)
    const v4f* __restrict__ c4,   // (3, E)
    v4f* __restrict__ out)        // (B, E)
{
    const int t  = blockIdx.x * blockDim.x + threadIdx.x;
    const int ev = t & (EV - 1);        // float4 column, fixed for this thread
    const int bt = t >> 9;              // b-group index, b = bt*BPT + i
    const int b0 = bt * BPT;

    // ---- weights: loaded ONCE, held in registers across all BPT rows ----
    v4f k1[2], k2[2], k3[3], k4[3];
    #pragma unroll
    for (int i = 0; i < 2; ++i) {
        k1[i] = c1[i * EV + ev];
        k2[i] = c2[i * EV + ev];
    }
    #pragma unroll
    for (int i = 0; i < 3; ++i) {
        k3[i] = c3[i * EV + ev];
        k4[i] = c4[i * EV + ev];
    }

    const v4f* xp = Xv + (size_t)b0 * SS * EV + ev;
    v4f*       op = out + (size_t)b0 * EV + ev;

    #pragma unroll 2
    for (int i = 0; i < BPT; ++i) {
        // ---- stream one sentence: 7 coalesced nontemporal 16B loads ----
        v4f xx[SS];
        #pragma unroll
        for (int s = 0; s < SS; ++s)
            xx[s] = __builtin_nontemporal_load(xp + s * EV);

        // ---- chain 7 -> 6 -> 5 -> 3 -> 1 per channel ----
        v4f r;
        #pragma unroll
        for (int j = 0; j < 4; ++j) {
            float y1[6];
            #pragma unroll
            for (int s = 0; s < 6; ++s)
                y1[s] = fast_tanh(fmaf(xx[s][j], k1[0][j], xx[s + 1][j] * k1[1][j]));
            float y2[5];
            #pragma unroll
            for (int s = 0; s < 5; ++s)
                y2[s] = fast_tanh(fmaf(y1[s], k2[0][j], y1[s + 1] * k2[1][j]));
            float y3[3];
            #pragma unroll
            for (int s = 0; s < 3; ++s)
                y3[s] = fast_tanh(fmaf(y2[s], k3[0][j],
                                  fmaf(y2[s + 1], k3[1][j], y2[s + 2] * k3[2][j])));
            r[j] = fast_tanh(fmaf(y3[0], k4[0][j],
                             fmaf(y3[1], k4[1][j], y3[2] * k4[2][j])));
        }

        __builtin_nontemporal_store(r, op);
        xp += SS * EV;
        op += EV;
    }
}

extern "C" void kernel_launch(void* const* d_in, const int* in_sizes, int n_in,
                              void* d_out, int out_size, void* d_ws, size_t ws_size,
                              hipStream_t stream) {
    const v4f* X  = (const v4f*)d_in[0];
    const v4f* c1 = (const v4f*)d_in[1];
    const v4f* c2 = (const v4f*)d_in[2];
    const v4f* c3 = (const v4f*)d_in[3];
    const v4f* c4 = (const v4f*)d_in[4];
    v4f* out = (v4f*)d_out;

    const int total_threads = EV * (BB / BPT);   // 512 * 1024 = 524288
    const int block = 256;
    const int grid  = total_threads / block;     // 2048 blocks = 8/CU
    CSM_62216896250027_kernel<<<grid, block, 0, stream>>>(X, c1, c2, c3, c4, out);
}

// Round 3
// 106.879 us; speedup vs baseline: 1.0451x; 1.0451x over previous
//
#include <hip/hip_runtime.h>

// Problem constants (match reference)
#define BB 8192
#define SS 7
#define EE 2048
#define EV2 (EE / 2)   // float2 groups per row = 1024
#define BPT 8          // batch rows per thread

typedef float v2f __attribute__((ext_vector_type(2)));

#define SC 2.885390081777927f   // 2*log2(e): folded into conv weights

// tanh(x) given s = 2*log2(e)*x : 1 - 2/(exp2(s)+1).
// Saturates correctly at +/-inf args (exp2->inf -> 1; exp2->0 -> -1).
__device__ __forceinline__ v2f tanh2(v2f s) {
    v2f e, r;
    e.x = exp2f(s.x);
    e.y = exp2f(s.y);
    v2f d = e + 1.0f;                 // v_pk_add
    r.x = __builtin_amdgcn_rcpf(d.x);
    r.y = __builtin_amdgcn_rcpf(d.y);
    return 1.0f - 2.0f * r;           // v_pk_fma
}

__global__ __launch_bounds__(256, 6) void CSM_62216896250027_kernel(
    const v2f* __restrict__ Xv,
    const v2f* __restrict__ c1,   // (2, E)
    const v2f* __restrict__ c2,   // (2, E)
    const v2f* __restrict__ c3,   // (3, E)
    const v2f* __restrict__ c4,   // (3, E)
    v2f* __restrict__ out)        // (B, E)
{
    const int t   = blockIdx.x * blockDim.x + threadIdx.x;
    const int ev  = t & (EV2 - 1);      // float2 column, fixed per thread
    const int bt  = t >> 10;            // b-group, rows b = bt*BPT + i
    const int b0  = bt * BPT;

    // ---- weights: loaded once, pre-scaled by 2*log2(e), held in regs ----
    v2f k1[2], k2[2], k3[3], k4[3];
    #pragma unroll
    for (int i = 0; i < 2; ++i) {
        k1[i] = c1[i * EV2 + ev] * SC;
        k2[i] = c2[i * EV2 + ev] * SC;
    }
    #pragma unroll
    for (int i = 0; i < 3; ++i) {
        k3[i] = c3[i * EV2 + ev] * SC;
        k4[i] = c4[i * EV2 + ev] * SC;
    }

    const v2f* xp = Xv + (size_t)b0 * SS * EV2 + ev;
    v2f*       op = out + (size_t)b0 * EV2 + ev;

    // ---- software pipeline: loads of row i+1 in flight during compute of i ----
    v2f xx[SS], xn[SS];
    #pragma unroll
    for (int s = 0; s < SS; ++s)
        xx[s] = __builtin_nontemporal_load(xp + s * EV2);
    xp += SS * EV2;

    #pragma unroll
    for (int i = 0; i < BPT; ++i) {
        if (i + 1 < BPT) {
            #pragma unroll
            for (int s = 0; s < SS; ++s)
                xn[s] = __builtin_nontemporal_load(xp + s * EV2);
            xp += SS * EV2;
        }

        // ---- chain 7 -> 6 -> 5 -> 3 -> 1, vectorized (v_pk_* math) ----
        v2f y1[6];
        #pragma unroll
        for (int s = 0; s < 6; ++s)
            y1[s] = tanh2(xx[s] * k1[0] + xx[s + 1] * k1[1]);
        v2f y2[5];
        #pragma unroll
        for (int s = 0; s < 5; ++s)
            y2[s] = tanh2(y1[s] * k2[0] + y1[s + 1] * k2[1]);
        v2f y3[3];
        #pragma unroll
        for (int s = 0; s < 3; ++s)
            y3[s] = tanh2(y2[s] * k3[0] + y2[s + 1] * k3[1] + y2[s + 2] * k3[2]);
        v2f y4 = tanh2(y3[0] * k4[0] + y3[1] * k4[1] + y3[2] * k4[2]);

        __builtin_nontemporal_store(y4, op);
        op += EV2;

        #pragma unroll
        for (int s = 0; s < SS; ++s)
            xx[s] = xn[s];
    }
}

extern "C" void kernel_launch(void* const* d_in, const int* in_sizes, int n_in,
                              void* d_out, int out_size, void* d_ws, size_t ws_size,
                              hipStream_t stream) {
    const v2f* X  = (const v2f*)d_in[0];
    const v2f* c1 = (const v2f*)d_in[1];
    const v2f* c2 = (const v2f*)d_in[2];
    const v2f* c3 = (const v2f*)d_in[3];
    const v2f* c4 = (const v2f*)d_in[4];
    v2f* out = (v2f*)d_out;

    const int total_threads = EV2 * (BB / BPT);  // 1024 * 1024 = 1,048,576
    const int block = 256;
    const int grid  = total_threads / block;     // 4096 blocks
    CSM_62216896250027_kernel<<<grid, block, 0, stream>>>(X, c1, c2, c3, c4, out);
}